// Round 6
// baseline (374.376 us; speedup 1.0000x reference)
//
#include <hip/hip_runtime.h>
#include <hip/hip_fp16.h>
#include <math.h>

#define NPTS   32768
#define CCH    128
#define FMH    480
#define FMW    640
#define PLANE  (FMH*FMW)
#define IMW    640
#define IMH    480
#define TPP    8           // threads per point
#define PPB    32          // points per block
#define NBLK   (NPTS/PPB)  // 1024
#define NPART  27          // 6 (g) + 21 (H upper triangle)
#define MSTR   8           // per-pixel map stride (floats)
#define PTILE  256         // pixels per prep block

__device__ __forceinline__ float f4e(const float4& v, int i){
    return i==0 ? v.x : i==1 ? v.y : i==2 ? v.z : v.w;
}

// ---------------------------------------------------------------------------
// One-time prep: per-pixel maps + (H*W, C) fp16-interleaved transpose of gx,gy.
// DRAM-burst version: block = 256 px tile; wave w owns channels 32w..32w+31.
// Each wave-instruction reads one channel's 1 KB contiguously (64 x float4).
// Thread owns 4 pixels; every 4 channels it stores one contiguous uint4 to gT,
// covering its pixels' 128B lines alone across 8 store groups (L2 merges).
// ---------------------------------------------------------------------------
__global__ __launch_bounds__(256)
void pnp_prep(const float* __restrict__ fmap,
              const float* __restrict__ gxm,
              const float* __restrict__ gym,
              __half2* __restrict__ gT,
              float* __restrict__ maps8)
{
    __shared__ float4 spart[4][5][64];     // 20,480 B
    const int tid  = threadIdx.x;
    const int lane = tid & 63;
    const int w    = tid >> 6;             // wave id: channel range 32w..32w+31
    const size_t p0 = (size_t)blockIdx.x * PTILE;
    const int pq   = lane * 4;             // this thread's pixel base in tile

    float acc[5][4];
    #pragma unroll
    for (int m=0;m<5;m++)
        #pragma unroll
        for (int i=0;i<4;i++) acc[m][i]=0.f;

    // 8 groups of 4 channels
    for (int rg=0; rg<8; ++rg){
        const int cbase = w*32 + rg*4;
        unsigned hb[4][4];                 // [pixel][channel-in-group]
        #pragma unroll
        for (int k=0;k<4;k++){
            const int c = cbase + k;
            const size_t off = (size_t)c*PLANE + p0 + pq;
            const float4 fv = *reinterpret_cast<const float4*>(fmap + off);
            const float4 av = *reinterpret_cast<const float4*>(gxm  + off);
            const float4 bv = *reinterpret_cast<const float4*>(gym  + off);
            #pragma unroll
            for (int i=0;i<4;i++){
                const float a = f4e(av,i);
                const float b = f4e(bv,i);
                const float f = f4e(fv,i);
                acc[0][i] = fmaf(a, f, acc[0][i]);
                acc[1][i] = fmaf(b, f, acc[1][i]);
                acc[2][i] = fmaf(a, a, acc[2][i]);
                acc[3][i] = fmaf(a, b, acc[3][i]);
                acc[4][i] = fmaf(b, b, acc[4][i]);
                const __half2 h = __floats2half2_rn(a, b);
                hb[i][k] = *reinterpret_cast<const unsigned*>(&h);
            }
        }
        #pragma unroll
        for (int i=0;i<4;i++){
            uint4 out;
            out.x=hb[i][0]; out.y=hb[i][1]; out.z=hb[i][2]; out.w=hb[i][3];
            *reinterpret_cast<uint4*>(&gT[(p0 + pq + i)*CCH + cbase]) = out;
        }
    }

    // stash this wave's 32-channel partial maps (float4 per thread: 4 pixels)
    #pragma unroll
    for (int m=0;m<5;m++){
        float4 v4; v4.x=acc[m][0]; v4.y=acc[m][1]; v4.z=acc[m][2]; v4.w=acc[m][3];
        spart[w][m][lane] = v4;
    }
    __syncthreads();

    // reduce across the 4 waves: thread t owns pixel t of the tile.
    {
        const int p = tid;
        const float* sp = reinterpret_cast<const float*>(&spart[0][0][0]);
        float s[5];
        #pragma unroll
        for (int m=0;m<5;m++){
            // layout: ((w*5 + m)*64 + p/4)*4 + (p&3)  ==  (w*5+m)*256 + p
            s[m] = sp[(0*5+m)*256 + p] + sp[(1*5+m)*256 + p]
                 + sp[(2*5+m)*256 + p] + sp[(3*5+m)*256 + p];
        }
        const size_t pix = p0 + p;
        float4 v4; v4.x=s[0]; v4.y=s[1]; v4.z=s[2]; v4.w=s[3];
        *reinterpret_cast<float4*>(&maps8[pix*MSTR]) = v4;
        maps8[pix*MSTR + 4] = s[4];
    }
}

// ---------------------------------------------------------------------------
// Per-iteration accumulate using fp16 transposed grads + packed pixel maps.
// ---------------------------------------------------------------------------
__global__ __launch_bounds__(256)
void pnp_accum2(const float* __restrict__ pts3D,
                const float* __restrict__ fref,
                const __half2* __restrict__ gT,
                const float* __restrict__ maps8,
                const float* __restrict__ Kmat,
                const float* __restrict__ Rsrc,
                const float* __restrict__ tsrc,
                float* __restrict__ partials)
{
    const int tid = threadIdx.x;
    const int g   = tid & (TPP-1);
    const int pl  = tid >> 3;
    const int n   = blockIdx.x * PPB + pl;

    const float R00=Rsrc[0],R01=Rsrc[1],R02=Rsrc[2];
    const float R10=Rsrc[3],R11=Rsrc[4],R12=Rsrc[5];
    const float R20=Rsrc[6],R21=Rsrc[7],R22=Rsrc[8];
    const float t0=tsrc[0],t1=tsrc[1],t2=tsrc[2];
    const float K00=Kmat[0],K01=Kmat[1],K02=Kmat[2];
    const float K10=Kmat[3],K11=Kmat[4],K12=Kmat[5];
    const float K20=Kmat[6],K21=Kmat[7],K22=Kmat[8];
    const float fx=K00, fy=K11;

    const float px=pts3D[n*3+0], py=pts3D[n*3+1], pz=pts3D[n*3+2];
    const float x = R00*px + R01*py + R02*pz + t0;
    const float y = R10*px + R11*py + R12*pz + t1;
    const float z = R20*px + R21*py + R22*pz + t2;
    const float phx = K00*x + K01*y + K02*z;
    const float phy = K10*x + K11*y + K12*z;
    const float phz = K20*x + K21*y + K22*z;
    const int p2x = (int)rintf(phx/phz) - 1;
    const int p2y = (int)rintf(phy/phz) - 1;
    const bool inb = (p2x>=0) && (p2y>=0) && (p2x<IMW) && (p2y<IMH);
    const int pix = inb ? (p2y*FMW + p2x) : 0;

    float dx=0.f, dy=0.f;
    if (inb) {
        const uint4*  gp = reinterpret_cast<const uint4*>(gT + (size_t)pix*CCH + g*16);
        const float4* rp = reinterpret_cast<const float4*>(fref + (size_t)n*CCH + g*16);
        #pragma unroll
        for (int j=0;j<4;j++){
            const uint4  wv = gp[j];
            const float4 r = rp[j];
            const float2 f0 = __half22float2(*reinterpret_cast<const __half2*>(&wv.x));
            const float2 f1 = __half22float2(*reinterpret_cast<const __half2*>(&wv.y));
            const float2 f2 = __half22float2(*reinterpret_cast<const __half2*>(&wv.z));
            const float2 f3 = __half22float2(*reinterpret_cast<const __half2*>(&wv.w));
            dx = fmaf(f0.x,r.x,dx); dy = fmaf(f0.y,r.x,dy);
            dx = fmaf(f1.x,r.y,dx); dy = fmaf(f1.y,r.y,dy);
            dx = fmaf(f2.x,r.z,dx); dy = fmaf(f2.y,r.z,dy);
            dx = fmaf(f3.x,r.w,dx); dy = fmaf(f3.y,r.w,dy);
        }
    }
    #pragma unroll
    for (int d=1; d<TPP; d<<=1){
        dx += __shfl_xor(dx, d);
        dy += __shfl_xor(dy, d);
    }

    float v[NPART];
    #pragma unroll
    for (int i=0;i<NPART;i++) v[i]=0.f;
    if (inb) {
        const float4 m03 = *reinterpret_cast<const float4*>(&maps8[(size_t)pix*MSTR]);
        const float  m4  = maps8[(size_t)pix*MSTR + 4];
        const float sx  = m03.x - dx;
        const float sy  = m03.y - dy;
        const float gxx = m03.z;
        const float gxy = m03.w;
        const float gyy = m4;

        const float zi = 1.f/z;
        const float a0 = fx*zi;
        const float b0 = -fx*x*zi*zi;
        const float c1 = fy*zi;
        const float d1 = -fy*y*zi*zi;
        const float A0[6] = {a0, 0.f, b0, b0*y, a0*z - b0*x, -a0*y};
        const float A1[6] = {0.f, c1, d1, -c1*z + d1*y, -d1*x, c1*x};
        #pragma unroll
        for (int i=0;i<6;i++) v[i] = A0[i]*sx + A1[i]*sy;
        int idx=6;
        #pragma unroll
        for (int i=0;i<6;i++){
            #pragma unroll
            for (int j=i;j<6;j++){
                v[idx] = gxx*A0[i]*A0[j]
                       + gxy*(A0[i]*A1[j]+A1[i]*A0[j])
                       + gyy*A1[i]*A1[j];
                idx++;
            }
        }
    }

    __shared__ float wpart[4][NPART];
    const int wid  = tid >> 6;
    const int lane = tid & 63;
    #pragma unroll
    for (int i=0;i<NPART;i++){
        float vv = v[i];
        vv += __shfl_xor(vv, 8);
        vv += __shfl_xor(vv, 16);
        vv += __shfl_xor(vv, 32);
        if (lane==0) wpart[wid][i]=vv;
    }
    __syncthreads();
    if (tid < NPART){
        partials[blockIdx.x*NPART + tid] =
            wpart[0][tid]+wpart[1][tid]+wpart[2][tid]+wpart[3][tid];
    }
}

// ---------------------------------------------------------------------------
// Fallback accum (round-1 path) if workspace is too small for transposes.
// ---------------------------------------------------------------------------
__global__ __launch_bounds__(256)
void pnp_accum(const float* __restrict__ pts3D,
               const float* __restrict__ fref,
               const float* __restrict__ fmap,
               const float* __restrict__ gxm,
               const float* __restrict__ gym,
               const float* __restrict__ Kmat,
               const float* __restrict__ Rsrc,
               const float* __restrict__ tsrc,
               float* __restrict__ partials)
{
    const int tid = threadIdx.x;
    const int g   = tid & (TPP-1);
    const int pl  = tid >> 3;
    const int n   = blockIdx.x * PPB + pl;

    const float R00=Rsrc[0],R01=Rsrc[1],R02=Rsrc[2];
    const float R10=Rsrc[3],R11=Rsrc[4],R12=Rsrc[5];
    const float R20=Rsrc[6],R21=Rsrc[7],R22=Rsrc[8];
    const float t0=tsrc[0],t1=tsrc[1],t2=tsrc[2];
    const float K00=Kmat[0],K01=Kmat[1],K02=Kmat[2];
    const float K10=Kmat[3],K11=Kmat[4],K12=Kmat[5];
    const float K20=Kmat[6],K21=Kmat[7],K22=Kmat[8];
    const float fx=K00, fy=K11;

    const float px=pts3D[n*3+0], py=pts3D[n*3+1], pz=pts3D[n*3+2];
    const float x = R00*px + R01*py + R02*pz + t0;
    const float y = R10*px + R11*py + R12*pz + t1;
    const float z = R20*px + R21*py + R22*pz + t2;
    const float phx = K00*x + K01*y + K02*z;
    const float phy = K10*x + K11*y + K12*z;
    const float phz = K20*x + K21*y + K22*z;
    const int p2x = (int)rintf(phx/phz) - 1;
    const int p2y = (int)rintf(phy/phz) - 1;
    const bool inb = (p2x>=0) && (p2y>=0) && (p2x<IMW) && (p2y<IMH);

    float sx=0.f, sy=0.f, gxx=0.f, gxy=0.f, gyy=0.f;
    if (inb) {
        const int pix = p2y*FMW + p2x;
        const float* fm = fmap + pix;
        const float* gx = gxm  + pix;
        const float* gy = gym  + pix;
        const float4* refp =
            reinterpret_cast<const float4*>(fref + (size_t)n*CCH + g*16);
        #pragma unroll
        for (int j=0;j<4;j++){
            const float4 rv = refp[j];
            const float rarr[4] = {rv.x, rv.y, rv.z, rv.w};
            const int c0 = g*16 + j*4;
            #pragma unroll
            for (int k=0;k<4;k++){
                const int off = (c0+k)*PLANE;
                const float f = fm[off];
                const float a = gx[off];
                const float b = gy[off];
                const float e = f - rarr[k];
                sx  = fmaf(a,e,sx);
                sy  = fmaf(b,e,sy);
                gxx = fmaf(a,a,gxx);
                gxy = fmaf(a,b,gxy);
                gyy = fmaf(b,b,gyy);
            }
        }
    }
    #pragma unroll
    for (int d=1; d<TPP; d<<=1){
        sx  += __shfl_xor(sx , d);
        sy  += __shfl_xor(sy , d);
        gxx += __shfl_xor(gxx, d);
        gxy += __shfl_xor(gxy, d);
        gyy += __shfl_xor(gyy, d);
    }

    float v[NPART];
    #pragma unroll
    for (int i=0;i<NPART;i++) v[i]=0.f;
    if (inb) {
        const float zi = 1.f/z;
        const float a0 = fx*zi;
        const float b0 = -fx*x*zi*zi;
        const float c1 = fy*zi;
        const float d1 = -fy*y*zi*zi;
        const float A0[6] = {a0, 0.f, b0, b0*y, a0*z - b0*x, -a0*y};
        const float A1[6] = {0.f, c1, d1, -c1*z + d1*y, -d1*x, c1*x};
        #pragma unroll
        for (int i=0;i<6;i++) v[i] = A0[i]*sx + A1[i]*sy;
        int idx=6;
        #pragma unroll
        for (int i=0;i<6;i++){
            #pragma unroll
            for (int j=i;j<6;j++){
                v[idx] = gxx*A0[i]*A0[j]
                       + gxy*(A0[i]*A1[j]+A1[i]*A0[j])
                       + gyy*A1[i]*A1[j];
                idx++;
            }
        }
    }

    __shared__ float wpart[4][NPART];
    const int wid  = tid >> 6;
    const int lane = tid & 63;
    #pragma unroll
    for (int i=0;i<NPART;i++){
        float vv = v[i];
        vv += __shfl_xor(vv, 8);
        vv += __shfl_xor(vv, 16);
        vv += __shfl_xor(vv, 32);
        if (lane==0) wpart[wid][i]=vv;
    }
    __syncthreads();
    if (tid < NPART){
        partials[blockIdx.x*NPART + tid] =
            wpart[0][tid]+wpart[1][tid]+wpart[2][tid]+wpart[3][tid];
    }
}

// ---------------------------------------------------------------------------
// Parallel-reduce partials, damp, solve 6x6, so3exp, update R,t.
// ---------------------------------------------------------------------------
__global__ void pnp_solve(const float* __restrict__ partials,
                          const float* __restrict__ Rsrc,
                          const float* __restrict__ tsrc,
                          float* __restrict__ RtWs,
                          float* __restrict__ outp)
{
    __shared__ double red[NPART*8];
    const int t = threadIdx.x;
    if (t < NPART*8){
        const int col = t % NPART;
        const int grp = t / NPART;
        double s0 = 0.0, s1 = 0.0;
        for (int p = grp; p < NBLK; p += 16){
            s0 += (double)partials[p*NPART + col];
            s1 += (double)partials[(p+8)*NPART + col];
        }
        red[col*8 + grp] = s0 + s1;
    }
    __syncthreads();
    if (t < NPART){
        double s = 0.0;
        #pragma unroll
        for (int k=0;k<8;k++) s += red[t*8 + k];
        red[t*8] = s;
    }
    __syncthreads();
    if (t==0){
        double gv[6]; double H[6][6];
        for (int i=0;i<6;i++) gv[i]=red[i*8];
        int idx=6;
        for (int i=0;i<6;i++)
            for (int j=i;j<6;j++){
                H[i][j]=red[idx*8]; H[j][i]=red[idx*8]; idx++;
            }
        for (int i=0;i<6;i++) H[i][i] += 0.01*(H[i][i] + 1e-9);

        double M[6][6], b[6];
        for (int i=0;i<6;i++){ b[i]=gv[i]; for (int j=0;j<6;j++) M[i][j]=H[i][j]; }
        for (int c=0;c<6;c++){
            int piv=c; double mx=fabs(M[c][c]);
            for (int r=c+1;r<6;r++){ double av=fabs(M[r][c]); if (av>mx){mx=av;piv=r;} }
            if (piv!=c){
                for (int j=c;j<6;j++){ double tmp=M[c][j]; M[c][j]=M[piv][j]; M[piv][j]=tmp; }
                double tb=b[c]; b[c]=b[piv]; b[piv]=tb;
            }
            const double inv = 1.0/M[c][c];
            for (int r=c+1;r<6;r++){
                const double f = M[r][c]*inv;
                for (int j=c;j<6;j++) M[r][j] -= f*M[c][j];
                b[r] -= f*b[c];
            }
        }
        double xs[6];
        for (int r=5;r>=0;r--){
            double s2=b[r];
            for (int j=r+1;j<6;j++) s2 -= M[r][j]*xs[j];
            xs[r]=s2/M[r][r];
        }
        double delta[6];
        for (int i=0;i<6;i++) delta[i] = -xs[i];

        const double wx=delta[3], wy=delta[4], wz=delta[5];
        const double th = sqrt(wx*wx+wy*wy+wz*wz + 1e-24);
        const double Ath = sin(th)/th;
        const double Bth = (1.0-cos(th))/(th*th);
        const double W[3][3] = {{0.0,-wz,wy},{wz,0.0,-wx},{-wy,wx,0.0}};
        double W2[3][3];
        for (int i=0;i<3;i++) for (int j=0;j<3;j++){
            double s2=0; for (int k2=0;k2<3;k2++) s2 += W[i][k2]*W[k2][j];
            W2[i][j]=s2;
        }
        double dR[3][3];
        for (int i=0;i<3;i++) for (int j=0;j<3;j++)
            dR[i][j] = (i==j?1.0:0.0) + Ath*W[i][j] + Bth*W2[i][j];

        double Ro[3][3];
        for (int i=0;i<3;i++) for (int j=0;j<3;j++) Ro[i][j]=(double)Rsrc[i*3+j];
        const double to0=(double)tsrc[0], to1=(double)tsrc[1], to2=(double)tsrc[2];

        double Rn[3][3], tn[3];
        for (int i=0;i<3;i++){
            for (int j=0;j<3;j++){
                double s2=0; for (int k2=0;k2<3;k2++) s2 += dR[i][k2]*Ro[k2][j];
                Rn[i][j]=s2;
            }
            tn[i] = dR[i][0]*to0 + dR[i][1]*to1 + dR[i][2]*to2 + delta[i];
        }
        for (int i=0;i<3;i++) for (int j=0;j<3;j++){
            RtWs[i*3+j] = (float)Rn[i][j];
            outp[i*3+j] = (float)Rn[i][j];
        }
        for (int i=0;i<3;i++){ RtWs[9+i]=(float)tn[i]; outp[9+i]=(float)tn[i]; }
    }
}

extern "C" void kernel_launch(void* const* d_in, const int* in_sizes, int n_in,
                              void* d_out, int out_size, void* d_ws, size_t ws_size,
                              hipStream_t stream)
{
    const float* pts   = (const float*)d_in[0];
    const float* fref  = (const float*)d_in[1];
    const float* fmap  = (const float*)d_in[2];
    const float* gxm   = (const float*)d_in[3];
    const float* gym   = (const float*)d_in[4];
    const float* Kmat  = (const float*)d_in[5];
    const float* Rin   = (const float*)d_in[6];
    const float* tin   = (const float*)d_in[7];
    float* outp = (float*)d_out;

    // workspace layout: [partials][RtWs][maps8(8*PLANE f32)][gT(PLANE*128 half2)]
    float* partials = (float*)d_ws;
    float* RtWs  = partials + NBLK*NPART;
    float* maps8 = RtWs + 12;
    __half2* gT  = reinterpret_cast<__half2*>(maps8 + (size_t)MSTR*PLANE);
    const size_t needed_bytes = ((size_t)NBLK*NPART + 12 + (size_t)MSTR*PLANE) * 4
                                + (size_t)PLANE*CCH * sizeof(__half2);

    const bool fast = (ws_size >= needed_bytes);
    if (fast){
        pnp_prep<<<PLANE/PTILE, 256, 0, stream>>>(fmap, gxm, gym, gT, maps8);
    }

    const float* Rs = Rin;
    const float* ts = tin;
    for (int it=0; it<5; ++it){
        if (fast){
            pnp_accum2<<<NBLK, 256, 0, stream>>>(pts, fref, gT, maps8,
                                                 Kmat, Rs, ts, partials);
        } else {
            pnp_accum<<<NBLK, 256, 0, stream>>>(pts, fref, fmap, gxm, gym,
                                                Kmat, Rs, ts, partials);
        }
        pnp_solve<<<1, 256, 0, stream>>>(partials, Rs, ts, RtWs, outp);
        Rs = RtWs; ts = RtWs + 9;
    }
}

// Round 7
// 283.759 us; speedup vs baseline: 1.3193x; 1.3193x over previous
//
#include <hip/hip_runtime.h>
#include <math.h>

#define NPTS   32768
#define CCH    128
#define FMH    480
#define FMW    640
#define PLANE  (FMH*FMW)
#define IMW    640
#define IMH    480
#define TPP    8           // threads per point
#define PPB    32          // points per block
#define NBLK   (NPTS/PPB)  // 1024
#define NPART  27          // 6 (g) + 21 (H upper triangle)
#define MSTR   8           // per-pixel map stride (floats)
#define ROWB   256         // gQ bytes per pixel row (128 ch x 2 int8)
#define SCL    200.0f      // int8 quant scale (|gx| max ~0.57 -> 114 < 127)
#define INVS   0.005f      // 1/SCL

__device__ __forceinline__ float f4e(const float4& v, int i){
    return i==0 ? v.x : i==1 ? v.y : i==2 ? v.z : v.w;
}

__device__ __forceinline__ int q8(float v){
    return (int)rintf(fminf(fmaxf(v*SCL, -127.f), 127.f));
}

__device__ __forceinline__ unsigned pack2(float a0,float b0,float a1,float b1){
    return (unsigned)(q8(a0)&255) | ((unsigned)(q8(b0)&255)<<8)
         | ((unsigned)(q8(a1)&255)<<16) | ((unsigned)(q8(b1)&255)<<24);
}

// decode one uint32 = 2 channels of (gx,gy) int8 pairs, fma into dx,dy
__device__ __forceinline__ void dec4(unsigned u, float rA, float rB,
                                     float& dx, float& dy){
    dx = fmaf((float)((int)(u<<24)>>24), rA, dx);
    dy = fmaf((float)((int)(u<<16)>>24), rA, dy);
    dx = fmaf((float)((int)(u<< 8)>>24), rB, dx);
    dy = fmaf((float)( (int)u     >>24), rB, dy);
}

// ---------------------------------------------------------------------------
// One-time prep: per-pixel maps (f32) + (H*W, C) int8-interleaved gx,gy.
// Round-5 structure (clean write-merging, 64-px tile, register transpose):
// thread owns 4 pixels x 8 contiguous channels (2 reps of 4).
// Per rep per pixel: one uint2 (8 B) store -> row is 256 B, merged in L2.
// ---------------------------------------------------------------------------
__global__ __launch_bounds__(256)
void pnp_prep(const float* __restrict__ fmap,
              const float* __restrict__ gxm,
              const float* __restrict__ gym,
              unsigned char* __restrict__ gQ,
              float* __restrict__ maps8)
{
    __shared__ float spart[4][5][64];      // 5,120 B
    const int tid = threadIdx.x;
    const int pq  = (tid & 15) * 4;        // pixel base within tile
    const int cqp = tid >> 4;              // channel-octet phase 0..15
    const int w   = tid >> 6;              // wave 0..3
    const size_t p0 = (size_t)blockIdx.x * 64;

    float acc[5][4];
    #pragma unroll
    for (int m=0;m<5;m++)
        #pragma unroll
        for (int i=0;i<4;i++) acc[m][i]=0.f;

    #pragma unroll
    for (int rep=0; rep<2; ++rep){
        const int c0 = cqp*8 + rep*4;          // 4 contiguous channels
        float4 gxv[4], gyv[4], fmv[4];
        #pragma unroll
        for (int j=0;j<4;j++){
            const size_t off = (size_t)(c0+j)*PLANE + p0 + pq;
            gxv[j] = *reinterpret_cast<const float4*>(gxm  + off);
            gyv[j] = *reinterpret_cast<const float4*>(gym  + off);
            fmv[j] = *reinterpret_cast<const float4*>(fmap + off);
        }
        #pragma unroll
        for (int i=0;i<4;i++){                 // pixel within quad
            float a[4], b[4];
            #pragma unroll
            for (int j=0;j<4;j++){             // channel within group
                a[j] = f4e(gxv[j], i);
                b[j] = f4e(gyv[j], i);
                const float f = f4e(fmv[j], i);
                acc[0][i] = fmaf(a[j], f, acc[0][i]);
                acc[1][i] = fmaf(b[j], f, acc[1][i]);
                acc[2][i] = fmaf(a[j], a[j], acc[2][i]);
                acc[3][i] = fmaf(a[j], b[j], acc[3][i]);
                acc[4][i] = fmaf(b[j], b[j], acc[4][i]);
            }
            uint2 st;
            st.x = pack2(a[0], b[0], a[1], b[1]);
            st.y = pack2(a[2], b[2], a[3], b[3]);
            const size_t byteoff = (p0 + pq + i)*ROWB + (size_t)cqp*16 + rep*8;
            *reinterpret_cast<uint2*>(gQ + byteoff) = st;
        }
    }

    // reduce maps across the 16 channel phases:
    // xor16/xor32 folds the 4 phases within this wave, LDS folds the 4 waves.
    const bool lo16 = ((tid >> 4) & 3) == 0;
    #pragma unroll
    for (int m=0;m<5;m++){
        #pragma unroll
        for (int i=0;i<4;i++){
            float v = acc[m][i];
            v += __shfl_xor(v, 16);
            v += __shfl_xor(v, 32);
            if (lo16) spart[w][m][pq+i] = v;
        }
    }
    __syncthreads();

    if (tid < 64){
        const size_t pix = p0 + tid;
        const float m0 = spart[0][0][tid]+spart[1][0][tid]+spart[2][0][tid]+spart[3][0][tid];
        const float m1 = spart[0][1][tid]+spart[1][1][tid]+spart[2][1][tid]+spart[3][1][tid];
        const float m2 = spart[0][2][tid]+spart[1][2][tid]+spart[2][2][tid]+spart[3][2][tid];
        const float m3 = spart[0][3][tid]+spart[1][3][tid]+spart[2][3][tid]+spart[3][3][tid];
        const float m4 = spart[0][4][tid]+spart[1][4][tid]+spart[2][4][tid]+spart[3][4][tid];
        float4 v4; v4.x=m0; v4.y=m1; v4.z=m2; v4.w=m3;
        *reinterpret_cast<float4*>(&maps8[pix*MSTR]) = v4;
        maps8[pix*MSTR + 4] = m4;
    }
}

// ---------------------------------------------------------------------------
// Per-iteration accumulate using int8 transposed grads + packed pixel maps.
// ---------------------------------------------------------------------------
__global__ __launch_bounds__(256)
void pnp_accum2(const float* __restrict__ pts3D,
                const float* __restrict__ fref,
                const unsigned char* __restrict__ gQ,
                const float* __restrict__ maps8,
                const float* __restrict__ Kmat,
                const float* __restrict__ Rsrc,
                const float* __restrict__ tsrc,
                float* __restrict__ partials)
{
    const int tid = threadIdx.x;
    const int g   = tid & (TPP-1);
    const int pl  = tid >> 3;
    const int n   = blockIdx.x * PPB + pl;

    const float R00=Rsrc[0],R01=Rsrc[1],R02=Rsrc[2];
    const float R10=Rsrc[3],R11=Rsrc[4],R12=Rsrc[5];
    const float R20=Rsrc[6],R21=Rsrc[7],R22=Rsrc[8];
    const float t0=tsrc[0],t1=tsrc[1],t2=tsrc[2];
    const float K00=Kmat[0],K01=Kmat[1],K02=Kmat[2];
    const float K10=Kmat[3],K11=Kmat[4],K12=Kmat[5];
    const float K20=Kmat[6],K21=Kmat[7],K22=Kmat[8];
    const float fx=K00, fy=K11;

    const float px=pts3D[n*3+0], py=pts3D[n*3+1], pz=pts3D[n*3+2];
    const float x = R00*px + R01*py + R02*pz + t0;
    const float y = R10*px + R11*py + R12*pz + t1;
    const float z = R20*px + R21*py + R22*pz + t2;
    const float phx = K00*x + K01*y + K02*z;
    const float phy = K10*x + K11*y + K12*z;
    const float phz = K20*x + K21*y + K22*z;
    const int p2x = (int)rintf(phx/phz) - 1;
    const int p2y = (int)rintf(phy/phz) - 1;
    const bool inb = (p2x>=0) && (p2y>=0) && (p2x<IMW) && (p2y<IMH);
    const int pix = inb ? (p2y*FMW + p2x) : 0;

    float dx=0.f, dy=0.f;
    if (inb) {
        const uint4* gp =
            reinterpret_cast<const uint4*>(gQ + (size_t)pix*ROWB + g*32);
        const float4* rp =
            reinterpret_cast<const float4*>(fref + (size_t)n*CCH + g*16);
        const uint4 q0 = gp[0];
        const uint4 q1 = gp[1];
        const float4 r0 = rp[0], r1 = rp[1], r2 = rp[2], r3 = rp[3];
        dec4(q0.x, r0.x, r0.y, dx, dy);
        dec4(q0.y, r0.z, r0.w, dx, dy);
        dec4(q0.z, r1.x, r1.y, dx, dy);
        dec4(q0.w, r1.z, r1.w, dx, dy);
        dec4(q1.x, r2.x, r2.y, dx, dy);
        dec4(q1.y, r2.z, r2.w, dx, dy);
        dec4(q1.z, r3.x, r3.y, dx, dy);
        dec4(q1.w, r3.z, r3.w, dx, dy);
        dx *= INVS; dy *= INVS;
    }
    #pragma unroll
    for (int d=1; d<TPP; d<<=1){
        dx += __shfl_xor(dx, d);
        dy += __shfl_xor(dy, d);
    }

    float v[NPART];
    #pragma unroll
    for (int i=0;i<NPART;i++) v[i]=0.f;
    if (inb) {
        const float4 m03 = *reinterpret_cast<const float4*>(&maps8[(size_t)pix*MSTR]);
        const float  m4  = maps8[(size_t)pix*MSTR + 4];
        const float sx  = m03.x - dx;
        const float sy  = m03.y - dy;
        const float gxx = m03.z;
        const float gxy = m03.w;
        const float gyy = m4;

        const float zi = 1.f/z;
        const float a0 = fx*zi;
        const float b0 = -fx*x*zi*zi;
        const float c1 = fy*zi;
        const float d1 = -fy*y*zi*zi;
        const float A0[6] = {a0, 0.f, b0, b0*y, a0*z - b0*x, -a0*y};
        const float A1[6] = {0.f, c1, d1, -c1*z + d1*y, -d1*x, c1*x};
        #pragma unroll
        for (int i=0;i<6;i++) v[i] = A0[i]*sx + A1[i]*sy;
        int idx=6;
        #pragma unroll
        for (int i=0;i<6;i++){
            #pragma unroll
            for (int j=i;j<6;j++){
                v[idx] = gxx*A0[i]*A0[j]
                       + gxy*(A0[i]*A1[j]+A1[i]*A0[j])
                       + gyy*A1[i]*A1[j];
                idx++;
            }
        }
    }

    __shared__ float wpart[4][NPART];
    const int wid  = tid >> 6;
    const int lane = tid & 63;
    #pragma unroll
    for (int i=0;i<NPART;i++){
        float vv = v[i];
        vv += __shfl_xor(vv, 8);
        vv += __shfl_xor(vv, 16);
        vv += __shfl_xor(vv, 32);
        if (lane==0) wpart[wid][i]=vv;
    }
    __syncthreads();
    if (tid < NPART){
        partials[blockIdx.x*NPART + tid] =
            wpart[0][tid]+wpart[1][tid]+wpart[2][tid]+wpart[3][tid];
    }
}

// ---------------------------------------------------------------------------
// Fallback accum (round-1 path) if workspace is too small for transposes.
// ---------------------------------------------------------------------------
__global__ __launch_bounds__(256)
void pnp_accum(const float* __restrict__ pts3D,
               const float* __restrict__ fref,
               const float* __restrict__ fmap,
               const float* __restrict__ gxm,
               const float* __restrict__ gym,
               const float* __restrict__ Kmat,
               const float* __restrict__ Rsrc,
               const float* __restrict__ tsrc,
               float* __restrict__ partials)
{
    const int tid = threadIdx.x;
    const int g   = tid & (TPP-1);
    const int pl  = tid >> 3;
    const int n   = blockIdx.x * PPB + pl;

    const float R00=Rsrc[0],R01=Rsrc[1],R02=Rsrc[2];
    const float R10=Rsrc[3],R11=Rsrc[4],R12=Rsrc[5];
    const float R20=Rsrc[6],R21=Rsrc[7],R22=Rsrc[8];
    const float t0=tsrc[0],t1=tsrc[1],t2=tsrc[2];
    const float K00=Kmat[0],K01=Kmat[1],K02=Kmat[2];
    const float K10=Kmat[3],K11=Kmat[4],K12=Kmat[5];
    const float K20=Kmat[6],K21=Kmat[7],K22=Kmat[8];
    const float fx=K00, fy=K11;

    const float px=pts3D[n*3+0], py=pts3D[n*3+1], pz=pts3D[n*3+2];
    const float x = R00*px + R01*py + R02*pz + t0;
    const float y = R10*px + R11*py + R12*pz + t1;
    const float z = R20*px + R21*py + R22*pz + t2;
    const float phx = K00*x + K01*y + K02*z;
    const float phy = K10*x + K11*y + K12*z;
    const float phz = K20*x + K21*y + K22*z;
    const int p2x = (int)rintf(phx/phz) - 1;
    const int p2y = (int)rintf(phy/phz) - 1;
    const bool inb = (p2x>=0) && (p2y>=0) && (p2x<IMW) && (p2y<IMH);

    float sx=0.f, sy=0.f, gxx=0.f, gxy=0.f, gyy=0.f;
    if (inb) {
        const int pix = p2y*FMW + p2x;
        const float* fm = fmap + pix;
        const float* gx = gxm  + pix;
        const float* gy = gym  + pix;
        const float4* refp =
            reinterpret_cast<const float4*>(fref + (size_t)n*CCH + g*16);
        #pragma unroll
        for (int j=0;j<4;j++){
            const float4 rv = refp[j];
            const float rarr[4] = {rv.x, rv.y, rv.z, rv.w};
            const int c0 = g*16 + j*4;
            #pragma unroll
            for (int k=0;k<4;k++){
                const int off = (c0+k)*PLANE;
                const float f = fm[off];
                const float a = gx[off];
                const float b = gy[off];
                const float e = f - rarr[k];
                sx  = fmaf(a,e,sx);
                sy  = fmaf(b,e,sy);
                gxx = fmaf(a,a,gxx);
                gxy = fmaf(a,b,gxy);
                gyy = fmaf(b,b,gyy);
            }
        }
    }
    #pragma unroll
    for (int d=1; d<TPP; d<<=1){
        sx  += __shfl_xor(sx , d);
        sy  += __shfl_xor(sy , d);
        gxx += __shfl_xor(gxx, d);
        gxy += __shfl_xor(gxy, d);
        gyy += __shfl_xor(gyy, d);
    }

    float v[NPART];
    #pragma unroll
    for (int i=0;i<NPART;i++) v[i]=0.f;
    if (inb) {
        const float zi = 1.f/z;
        const float a0 = fx*zi;
        const float b0 = -fx*x*zi*zi;
        const float c1 = fy*zi;
        const float d1 = -fy*y*zi*zi;
        const float A0[6] = {a0, 0.f, b0, b0*y, a0*z - b0*x, -a0*y};
        const float A1[6] = {0.f, c1, d1, -c1*z + d1*y, -d1*x, c1*x};
        #pragma unroll
        for (int i=0;i<6;i++) v[i] = A0[i]*sx + A1[i]*sy;
        int idx=6;
        #pragma unroll
        for (int i=0;i<6;i++){
            #pragma unroll
            for (int j=i;j<6;j++){
                v[idx] = gxx*A0[i]*A0[j]
                       + gxy*(A0[i]*A1[j]+A1[i]*A0[j])
                       + gyy*A1[i]*A1[j];
                idx++;
            }
        }
    }

    __shared__ float wpart[4][NPART];
    const int wid  = tid >> 6;
    const int lane = tid & 63;
    #pragma unroll
    for (int i=0;i<NPART;i++){
        float vv = v[i];
        vv += __shfl_xor(vv, 8);
        vv += __shfl_xor(vv, 16);
        vv += __shfl_xor(vv, 32);
        if (lane==0) wpart[wid][i]=vv;
    }
    __syncthreads();
    if (tid < NPART){
        partials[blockIdx.x*NPART + tid] =
            wpart[0][tid]+wpart[1][tid]+wpart[2][tid]+wpart[3][tid];
    }
}

// ---------------------------------------------------------------------------
// Parallel-reduce partials, damp, solve 6x6, so3exp, update R,t.
// ---------------------------------------------------------------------------
__global__ void pnp_solve(const float* __restrict__ partials,
                          const float* __restrict__ Rsrc,
                          const float* __restrict__ tsrc,
                          float* __restrict__ RtWs,
                          float* __restrict__ outp)
{
    __shared__ double red[NPART*8];
    const int t = threadIdx.x;
    if (t < NPART*8){
        const int col = t % NPART;
        const int grp = t / NPART;
        double s0 = 0.0, s1 = 0.0;
        for (int p = grp; p < NBLK; p += 16){
            s0 += (double)partials[p*NPART + col];
            s1 += (double)partials[(p+8)*NPART + col];
        }
        red[col*8 + grp] = s0 + s1;
    }
    __syncthreads();
    if (t < NPART){
        double s = 0.0;
        #pragma unroll
        for (int k=0;k<8;k++) s += red[t*8 + k];
        red[t*8] = s;
    }
    __syncthreads();
    if (t==0){
        double gv[6]; double H[6][6];
        for (int i=0;i<6;i++) gv[i]=red[i*8];
        int idx=6;
        for (int i=0;i<6;i++)
            for (int j=i;j<6;j++){
                H[i][j]=red[idx*8]; H[j][i]=red[idx*8]; idx++;
            }
        for (int i=0;i<6;i++) H[i][i] += 0.01*(H[i][i] + 1e-9);

        double M[6][6], b[6];
        for (int i=0;i<6;i++){ b[i]=gv[i]; for (int j=0;j<6;j++) M[i][j]=H[i][j]; }
        for (int c=0;c<6;c++){
            int piv=c; double mx=fabs(M[c][c]);
            for (int r=c+1;r<6;r++){ double av=fabs(M[r][c]); if (av>mx){mx=av;piv=r;} }
            if (piv!=c){
                for (int j=c;j<6;j++){ double tmp=M[c][j]; M[c][j]=M[piv][j]; M[piv][j]=tmp; }
                double tb=b[c]; b[c]=b[piv]; b[piv]=tb;
            }
            const double inv = 1.0/M[c][c];
            for (int r=c+1;r<6;r++){
                const double f = M[r][c]*inv;
                for (int j=c;j<6;j++) M[r][j] -= f*M[c][j];
                b[r] -= f*b[c];
            }
        }
        double xs[6];
        for (int r=5;r>=0;r--){
            double s2=b[r];
            for (int j=r+1;j<6;j++) s2 -= M[r][j]*xs[j];
            xs[r]=s2/M[r][r];
        }
        double delta[6];
        for (int i=0;i<6;i++) delta[i] = -xs[i];

        const double wx=delta[3], wy=delta[4], wz=delta[5];
        const double th = sqrt(wx*wx+wy*wy+wz*wz + 1e-24);
        const double Ath = sin(th)/th;
        const double Bth = (1.0-cos(th))/(th*th);
        const double W[3][3] = {{0.0,-wz,wy},{wz,0.0,-wx},{-wy,wx,0.0}};
        double W2[3][3];
        for (int i=0;i<3;i++) for (int j=0;j<3;j++){
            double s2=0; for (int k2=0;k2<3;k2++) s2 += W[i][k2]*W[k2][j];
            W2[i][j]=s2;
        }
        double dR[3][3];
        for (int i=0;i<3;i++) for (int j=0;j<3;j++)
            dR[i][j] = (i==j?1.0:0.0) + Ath*W[i][j] + Bth*W2[i][j];

        double Ro[3][3];
        for (int i=0;i<3;i++) for (int j=0;j<3;j++) Ro[i][j]=(double)Rsrc[i*3+j];
        const double to0=(double)tsrc[0], to1=(double)tsrc[1], to2=(double)tsrc[2];

        double Rn[3][3], tn[3];
        for (int i=0;i<3;i++){
            for (int j=0;j<3;j++){
                double s2=0; for (int k2=0;k2<3;k2++) s2 += dR[i][k2]*Ro[k2][j];
                Rn[i][j]=s2;
            }
            tn[i] = dR[i][0]*to0 + dR[i][1]*to1 + dR[i][2]*to2 + delta[i];
        }
        for (int i=0;i<3;i++) for (int j=0;j<3;j++){
            RtWs[i*3+j] = (float)Rn[i][j];
            outp[i*3+j] = (float)Rn[i][j];
        }
        for (int i=0;i<3;i++){ RtWs[9+i]=(float)tn[i]; outp[9+i]=(float)tn[i]; }
    }
}

extern "C" void kernel_launch(void* const* d_in, const int* in_sizes, int n_in,
                              void* d_out, int out_size, void* d_ws, size_t ws_size,
                              hipStream_t stream)
{
    const float* pts   = (const float*)d_in[0];
    const float* fref  = (const float*)d_in[1];
    const float* fmap  = (const float*)d_in[2];
    const float* gxm   = (const float*)d_in[3];
    const float* gym   = (const float*)d_in[4];
    const float* Kmat  = (const float*)d_in[5];
    const float* Rin   = (const float*)d_in[6];
    const float* tin   = (const float*)d_in[7];
    float* outp = (float*)d_out;

    // workspace layout: [partials][RtWs][maps8(8*PLANE f32)][gQ(PLANE*256 B)]
    float* partials = (float*)d_ws;
    float* RtWs  = partials + NBLK*NPART;
    float* maps8 = RtWs + 12;
    unsigned char* gQ = reinterpret_cast<unsigned char*>(maps8 + (size_t)MSTR*PLANE);
    const size_t needed_bytes = ((size_t)NBLK*NPART + 12 + (size_t)MSTR*PLANE) * 4
                                + (size_t)PLANE*ROWB;

    const bool fast = (ws_size >= needed_bytes);
    if (fast){
        pnp_prep<<<PLANE/64, 256, 0, stream>>>(fmap, gxm, gym, gQ, maps8);
    }

    const float* Rs = Rin;
    const float* ts = tin;
    for (int it=0; it<5; ++it){
        if (fast){
            pnp_accum2<<<NBLK, 256, 0, stream>>>(pts, fref, gQ, maps8,
                                                 Kmat, Rs, ts, partials);
        } else {
            pnp_accum<<<NBLK, 256, 0, stream>>>(pts, fref, fmap, gxm, gym,
                                                Kmat, Rs, ts, partials);
        }
        pnp_solve<<<1, 256, 0, stream>>>(partials, Rs, ts, RtWs, outp);
        Rs = RtWs; ts = RtWs + 9;
    }
}

// Round 11
// 232.894 us; speedup vs baseline: 1.6075x; 1.2184x over previous
//
#include <hip/hip_runtime.h>
#include <math.h>

#define NPTS   32768
#define CCH    128
#define FMH    480
#define FMW    640
#define PLANE  (FMH*FMW)
#define IMW    640
#define IMH    480
#define PPB    16          // points per accum block (TPP=16 lanes/point)
#define NBLKA  (NPTS/PPB)  // 2048 accum blocks
#define NPART  27          // 6 (g) + 21 (H upper triangle)
#define MSTR   8           // per-pixel map stride (floats)
#define ROWB   256         // gQ bytes per pixel row (128 ch x 2 int8)
#define SCL    200.0f      // int8 quant scale (|gx| max ~0.57 -> 114 < 127)
#define INVS   0.005f      // 1/SCL

typedef float vfloat4 __attribute__((ext_vector_type(4)));

__device__ __forceinline__ float f4e(const float4& v, int i){
    return i==0 ? v.x : i==1 ? v.y : i==2 ? v.z : v.w;
}

__device__ __forceinline__ int q8(float v){
    return (int)rintf(fminf(fmaxf(v*SCL, -127.f), 127.f));
}

__device__ __forceinline__ unsigned pack2(float a0,float b0,float a1,float b1){
    return (unsigned)(q8(a0)&255) | ((unsigned)(q8(b0)&255)<<8)
         | ((unsigned)(q8(a1)&255)<<16) | ((unsigned)(q8(b1)&255)<<24);
}

// decode one uint32 = 2 channels of (gx,gy) int8 pairs, fma into dx,dy
__device__ __forceinline__ void dec4(unsigned u, float rA, float rB,
                                     float& dx, float& dy){
    dx = fmaf((float)((int)(u<<24)>>24), rA, dx);
    dy = fmaf((float)((int)(u<<16)>>24), rA, dy);
    dx = fmaf((float)((int)(u<< 8)>>24), rB, dx);
    dy = fmaf((float)( (int)u     >>24), rB, dy);
}

__device__ __forceinline__ float4 ntload4(const float* p){
    vfloat4 v = __builtin_nontemporal_load(reinterpret_cast<const vfloat4*>(p));
    return make_float4(v.x, v.y, v.z, v.w);
}

// ---------------------------------------------------------------------------
// One-time prep: per-pixel maps (f32) + (H*W, C) int8-interleaved gx,gy.
// 64-px tile, register transpose, nontemporal input reads (single-use).
// ---------------------------------------------------------------------------
__global__ __launch_bounds__(256)
void pnp_prep(const float* __restrict__ fmap,
              const float* __restrict__ gxm,
              const float* __restrict__ gym,
              unsigned char* __restrict__ gQ,
              float* __restrict__ maps8)
{
    __shared__ float spart[4][5][64];      // 5,120 B
    const int tid = threadIdx.x;
    const int pq  = (tid & 15) * 4;        // pixel base within tile
    const int cqp = tid >> 4;              // channel-octet phase 0..15
    const int w   = tid >> 6;              // wave 0..3
    const size_t p0 = (size_t)blockIdx.x * 64;

    float acc[5][4];
    #pragma unroll
    for (int m=0;m<5;m++)
        #pragma unroll
        for (int i=0;i<4;i++) acc[m][i]=0.f;

    #pragma unroll
    for (int rep=0; rep<2; ++rep){
        const int c0 = cqp*8 + rep*4;          // 4 contiguous channels
        float4 gxv[4], gyv[4], fmv[4];
        #pragma unroll
        for (int j=0;j<4;j++){
            const size_t off = (size_t)(c0+j)*PLANE + p0 + pq;
            gxv[j] = ntload4(gxm  + off);
            gyv[j] = ntload4(gym  + off);
            fmv[j] = ntload4(fmap + off);
        }
        #pragma unroll
        for (int i=0;i<4;i++){                 // pixel within quad
            float a[4], b[4];
            #pragma unroll
            for (int j=0;j<4;j++){             // channel within group
                a[j] = f4e(gxv[j], i);
                b[j] = f4e(gyv[j], i);
                const float f = f4e(fmv[j], i);
                acc[0][i] = fmaf(a[j], f, acc[0][i]);
                acc[1][i] = fmaf(b[j], f, acc[1][i]);
                acc[2][i] = fmaf(a[j], a[j], acc[2][i]);
                acc[3][i] = fmaf(a[j], b[j], acc[3][i]);
                acc[4][i] = fmaf(b[j], b[j], acc[4][i]);
            }
            uint2 st;
            st.x = pack2(a[0], b[0], a[1], b[1]);
            st.y = pack2(a[2], b[2], a[3], b[3]);
            const size_t byteoff = (p0 + pq + i)*ROWB + (size_t)cqp*16 + rep*8;
            *reinterpret_cast<uint2*>(gQ + byteoff) = st;
        }
    }

    // reduce maps across the 16 channel phases:
    // xor16/xor32 folds the 4 phases within this wave, LDS folds the 4 waves.
    const bool lo16 = ((tid >> 4) & 3) == 0;
    #pragma unroll
    for (int m=0;m<5;m++){
        #pragma unroll
        for (int i=0;i<4;i++){
            float v = acc[m][i];
            v += __shfl_xor(v, 16);
            v += __shfl_xor(v, 32);
            if (lo16) spart[w][m][pq+i] = v;
        }
    }
    __syncthreads();

    if (tid < 64){
        const size_t pix = p0 + tid;
        const float m0 = spart[0][0][tid]+spart[1][0][tid]+spart[2][0][tid]+spart[3][0][tid];
        const float m1 = spart[0][1][tid]+spart[1][1][tid]+spart[2][1][tid]+spart[3][1][tid];
        const float m2 = spart[0][2][tid]+spart[1][2][tid]+spart[2][2][tid]+spart[3][2][tid];
        const float m3 = spart[0][3][tid]+spart[1][3][tid]+spart[2][3][tid]+spart[3][3][tid];
        const float m4 = spart[0][4][tid]+spart[1][4][tid]+spart[2][4][tid]+spart[3][4][tid];
        float4 v4; v4.x=m0; v4.y=m1; v4.z=m2; v4.w=m3;
        *reinterpret_cast<float4*>(&maps8[pix*MSTR]) = v4;
        maps8[pix*MSTR + 4] = m4;
    }
}

// ---------------------------------------------------------------------------
// Per-iteration accumulate: 16 lanes/point, 2048 blocks.
// fref loads issued BEFORE the projection chain (address independent of R,t).
// Partials written COLUMN-MAJOR: partials[col*NBLKA + blk].
// ---------------------------------------------------------------------------
__global__ __launch_bounds__(256)
void pnp_accum2(const float* __restrict__ pts3D,
                const float* __restrict__ fref,
                const unsigned char* __restrict__ gQ,
                const float* __restrict__ maps8,
                const float* __restrict__ Kmat,
                const float* __restrict__ Rsrc,
                const float* __restrict__ tsrc,
                float* __restrict__ partials)
{
    const int tid = threadIdx.x;
    const int g   = tid & 15;          // channel octet lane
    const int pl  = tid >> 4;          // point slot 0..15
    const int n   = blockIdx.x * PPB + pl;

    // issue fref stream loads first -- independent of R,t chain
    const float4* rp = reinterpret_cast<const float4*>(fref + (size_t)n*CCH + g*8);
    const float4 r0 = rp[0];
    const float4 r1 = rp[1];

    const float R00=Rsrc[0],R01=Rsrc[1],R02=Rsrc[2];
    const float R10=Rsrc[3],R11=Rsrc[4],R12=Rsrc[5];
    const float R20=Rsrc[6],R21=Rsrc[7],R22=Rsrc[8];
    const float t0=tsrc[0],t1=tsrc[1],t2=tsrc[2];
    const float K00=Kmat[0],K01=Kmat[1],K02=Kmat[2];
    const float K10=Kmat[3],K11=Kmat[4],K12=Kmat[5];
    const float K20=Kmat[6],K21=Kmat[7],K22=Kmat[8];
    const float fx=K00, fy=K11;

    const float px=pts3D[n*3+0], py=pts3D[n*3+1], pz=pts3D[n*3+2];
    const float x = R00*px + R01*py + R02*pz + t0;
    const float y = R10*px + R11*py + R12*pz + t1;
    const float z = R20*px + R21*py + R22*pz + t2;
    const float phx = K00*x + K01*y + K02*z;
    const float phy = K10*x + K11*y + K12*z;
    const float phz = K20*x + K21*y + K22*z;
    const int p2x = (int)rintf(phx/phz) - 1;
    const int p2y = (int)rintf(phy/phz) - 1;
    const bool inb = (p2x>=0) && (p2y>=0) && (p2x<IMW) && (p2y<IMH);
    const int pix = inb ? (p2y*FMW + p2x) : 0;

    float dx=0.f, dy=0.f;
    if (inb) {
        const uint4 q =
            *reinterpret_cast<const uint4*>(gQ + (size_t)pix*ROWB + g*16);
        dec4(q.x, r0.x, r0.y, dx, dy);
        dec4(q.y, r0.z, r0.w, dx, dy);
        dec4(q.z, r1.x, r1.y, dx, dy);
        dec4(q.w, r1.z, r1.w, dx, dy);
        dx *= INVS; dy *= INVS;
    }
    #pragma unroll
    for (int d=1; d<16; d<<=1){
        dx += __shfl_xor(dx, d);
        dy += __shfl_xor(dy, d);
    }

    float v[NPART];
    #pragma unroll
    for (int i=0;i<NPART;i++) v[i]=0.f;
    if (inb) {
        const float4 m03 = *reinterpret_cast<const float4*>(&maps8[(size_t)pix*MSTR]);
        const float  m4  = maps8[(size_t)pix*MSTR + 4];
        const float sx  = m03.x - dx;
        const float sy  = m03.y - dy;
        const float gxx = m03.z;
        const float gxy = m03.w;
        const float gyy = m4;

        const float zi = 1.f/z;
        const float a0 = fx*zi;
        const float b0 = -fx*x*zi*zi;
        const float c1 = fy*zi;
        const float d1 = -fy*y*zi*zi;
        const float A0[6] = {a0, 0.f, b0, b0*y, a0*z - b0*x, -a0*y};
        const float A1[6] = {0.f, c1, d1, -c1*z + d1*y, -d1*x, c1*x};
        #pragma unroll
        for (int i=0;i<6;i++) v[i] = A0[i]*sx + A1[i]*sy;
        int idx=6;
        #pragma unroll
        for (int i=0;i<6;i++){
            #pragma unroll
            for (int j=i;j<6;j++){
                v[idx] = gxx*A0[i]*A0[j]
                       + gxy*(A0[i]*A1[j]+A1[i]*A0[j])
                       + gyy*A1[i]*A1[j];
                idx++;
            }
        }
    }

    // block reduce: xor16/xor32 folds the 4 points in this wave, LDS folds waves
    __shared__ float wpart[4][NPART];
    const int wid  = tid >> 6;
    const int lane = tid & 63;
    #pragma unroll
    for (int i=0;i<NPART;i++){
        float vv = v[i];
        vv += __shfl_xor(vv, 16);
        vv += __shfl_xor(vv, 32);
        if (lane==0) wpart[wid][i]=vv;
    }
    __syncthreads();
    if (tid < NPART){
        partials[(size_t)tid*NBLKA + blockIdx.x] =
            wpart[0][tid]+wpart[1][tid]+wpart[2][tid]+wpart[3][tid];
    }
}

// ---------------------------------------------------------------------------
// Parallel-reduce column-major partials (8 threads/column, contiguous float4
// sweeps), damp, solve 6x6, so3exp, update R,t.
// ---------------------------------------------------------------------------
__global__ void pnp_solve(const float* __restrict__ partials,
                          const float* __restrict__ Rsrc,
                          const float* __restrict__ tsrc,
                          float* __restrict__ RtWs,
                          float* __restrict__ outp)
{
    __shared__ double red[NPART];
    const int t = threadIdx.x;
    if (t < NPART*8){
        const int col = t >> 3;
        const int k   = t & 7;
        const float4* p4 =
            reinterpret_cast<const float4*>(partials + (size_t)col*NBLKA) + k*64;
        double s = 0.0;
        #pragma unroll 4
        for (int i=0;i<64;i++){
            const float4 v = p4[i];
            s += (double)v.x + (double)v.y + (double)v.z + (double)v.w;
        }
        s += __shfl_xor(s, 1);
        s += __shfl_xor(s, 2);
        s += __shfl_xor(s, 4);
        if (k==0) red[col] = s;
    }
    __syncthreads();
    if (t==0){
        double gv[6]; double H[6][6];
        for (int i=0;i<6;i++) gv[i]=red[i];
        int idx=6;
        for (int i=0;i<6;i++)
            for (int j=i;j<6;j++){
                H[i][j]=red[idx]; H[j][i]=red[idx]; idx++;
            }
        for (int i=0;i<6;i++) H[i][i] += 0.01*(H[i][i] + 1e-9);

        double M[6][6], b[6];
        for (int i=0;i<6;i++){ b[i]=gv[i]; for (int j=0;j<6;j++) M[i][j]=H[i][j]; }
        for (int c=0;c<6;c++){
            int piv=c; double mx=fabs(M[c][c]);
            for (int r=c+1;r<6;r++){ double av=fabs(M[r][c]); if (av>mx){mx=av;piv=r;} }
            if (piv!=c){
                for (int j=c;j<6;j++){ double tmp=M[c][j]; M[c][j]=M[piv][j]; M[piv][j]=tmp; }
                double tb=b[c]; b[c]=b[piv]; b[piv]=tb;
            }
            const double inv = 1.0/M[c][c];
            for (int r=c+1;r<6;r++){
                const double f = M[r][c]*inv;
                for (int j=c;j<6;j++) M[r][j] -= f*M[c][j];
                b[r] -= f*b[c];
            }
        }
        double xs[6];
        for (int r=5;r>=0;r--){
            double s2=b[r];
            for (int j=r+1;j<6;j++) s2 -= M[r][j]*xs[j];
            xs[r]=s2/M[r][r];
        }
        double delta[6];
        for (int i=0;i<6;i++) delta[i] = -xs[i];

        const double wx=delta[3], wy=delta[4], wz=delta[5];
        const double th = sqrt(wx*wx+wy*wy+wz*wz + 1e-24);
        const double Ath = sin(th)/th;
        const double Bth = (1.0-cos(th))/(th*th);
        const double W[3][3] = {{0.0,-wz,wy},{wz,0.0,-wx},{-wy,wx,0.0}};
        double W2[3][3];
        for (int i=0;i<3;i++) for (int j=0;j<3;j++){
            double s2=0; for (int k2=0;k2<3;k2++) s2 += W[i][k2]*W[k2][j];
            W2[i][j]=s2;
        }
        double dR[3][3];
        for (int i=0;i<3;i++) for (int j=0;j<3;j++)
            dR[i][j] = (i==j?1.0:0.0) + Ath*W[i][j] + Bth*W2[i][j];

        double Ro[3][3];
        for (int i=0;i<3;i++) for (int j=0;j<3;j++) Ro[i][j]=(double)Rsrc[i*3+j];
        const double to0=(double)tsrc[0], to1=(double)tsrc[1], to2=(double)tsrc[2];

        double Rn[3][3], tn[3];
        for (int i=0;i<3;i++){
            for (int j=0;j<3;j++){
                double s2=0; for (int k2=0;k2<3;k2++) s2 += dR[i][k2]*Ro[k2][j];
                Rn[i][j]=s2;
            }
            tn[i] = dR[i][0]*to0 + dR[i][1]*to1 + dR[i][2]*to2 + delta[i];
        }
        for (int i=0;i<3;i++) for (int j=0;j<3;j++){
            RtWs[i*3+j] = (float)Rn[i][j];
            outp[i*3+j] = (float)Rn[i][j];
        }
        for (int i=0;i<3;i++){ RtWs[9+i]=(float)tn[i]; outp[9+i]=(float)tn[i]; }
    }
}

extern "C" void kernel_launch(void* const* d_in, const int* in_sizes, int n_in,
                              void* d_out, int out_size, void* d_ws, size_t ws_size,
                              hipStream_t stream)
{
    const float* pts   = (const float*)d_in[0];
    const float* fref  = (const float*)d_in[1];
    const float* fmap  = (const float*)d_in[2];
    const float* gxm   = (const float*)d_in[3];
    const float* gym   = (const float*)d_in[4];
    const float* Kmat  = (const float*)d_in[5];
    const float* Rin   = (const float*)d_in[6];
    const float* tin   = (const float*)d_in[7];
    float* outp = (float*)d_out;

    // workspace layout: [partials(27*2048)][RtWs][maps8(8*PLANE f32)][gQ(PLANE*256 B)]
    float* partials = (float*)d_ws;
    float* RtWs  = partials + (size_t)NPART*NBLKA;
    float* maps8 = RtWs + 12;
    unsigned char* gQ = reinterpret_cast<unsigned char*>(maps8 + (size_t)MSTR*PLANE);

    pnp_prep<<<PLANE/64, 256, 0, stream>>>(fmap, gxm, gym, gQ, maps8);

    const float* Rs = Rin;
    const float* ts = tin;
    for (int it=0; it<5; ++it){
        pnp_accum2<<<NBLKA, 256, 0, stream>>>(pts, fref, gQ, maps8,
                                              Kmat, Rs, ts, partials);
        pnp_solve<<<1, 256, 0, stream>>>(partials, Rs, ts, RtWs, outp);
        Rs = RtWs; ts = RtWs + 9;
    }
}